// Round 10
// baseline (172.172 us; speedup 1.0000x reference)
//
#include <hip/hip_runtime.h>
#include <hip/hip_bf16.h>

using bf16 = __bf16;
typedef __attribute__((ext_vector_type(4))) bf16 bf16x4;
typedef __attribute__((ext_vector_type(8))) bf16 bf16x8;
typedef __attribute__((ext_vector_type(4))) float f32x4;
typedef __attribute__((ext_vector_type(16))) float f32x16;

constexpr int kB = 4, kS = 2048, kH = 1024, kNH = 16, kHD = 64;
constexpr int kM = kB * kS;  // 8192

__device__ __forceinline__ float exp2a(float x) {
  float r;
  asm("v_exp_f32 %0, %1" : "=v"(r) : "v"(x));
  return r;
}
// packed f32x2 -> bf16x2 (lo = a, hi = b), single instruction (T12)
__device__ __forceinline__ unsigned cvtpk(float a, float b) {
  unsigned r;
  asm("v_cvt_pk_bf16_f32 %0, %1, %2" : "=v"(r) : "v"(a), "v"(b));
  return r;
}
// async global->LDS, 16B per lane; LDS dest = wave-uniform base + lane*16
__device__ __forceinline__ void glds16(const bf16* g, bf16* l) {
  __builtin_amdgcn_global_load_lds(
      (const __attribute__((address_space(1))) unsigned*)g,
      (__attribute__((address_space(3))) unsigned*)l, 16, 0, 0);
}

// ---------------------------------------------------------------------------
// fused fp32 -> bf16 conversion (x + 4 weight matrices) in one launch
// ---------------------------------------------------------------------------
__global__ __launch_bounds__(256) void cvt_all_kernel(
    const float* __restrict__ x, const float* __restrict__ w0,
    const float* __restrict__ w1, const float* __restrict__ w2,
    const float* __restrict__ w3, bf16* __restrict__ xb,
    bf16* __restrict__ wb) {
  const int blk = blockIdx.x;
  const float* src;
  bf16* dst;
  int rel;
  if (blk < kM) {
    src = x; dst = xb; rel = blk;
  } else {
    const int wi = (blk - kM) >> 10;
    rel = (blk - kM) & 1023;
    src = wi == 0 ? w0 : wi == 1 ? w1 : wi == 2 ? w2 : w3;
    dst = wb + (size_t)wi * kH * kH;
  }
  const size_t i = (size_t)rel * 256 + threadIdx.x;
  const float4 f = ((const float4*)src)[i];
  bf16x4 o;
  o[0] = (bf16)f.x; o[1] = (bf16)f.y; o[2] = (bf16)f.z; o[3] = (bf16)f.w;
  ((bf16x4*)dst)[i] = o;
}

// ---------------------------------------------------------------------------
// bf16 MFMA GEMM, T3-minimum 2-phase: C = (A @ W^T + bias) * scale.
// 128x128 tile, BK=32, 4 waves.  Double-buffered LDS (2x16KB); next tile's
// global_load_lds issued BEFORE computing the current tile; ONE barrier per
// K-step (its implicit vmcnt(0)+lgkmcnt(0) drain = the recipe's wait, after
// the compute window has hidden the load latency).  Manual 2x unroll gives
// static buffer indices.
// MODE 0: fp32 [M][kH].  MODE 1: bf16 (b,h,s,d).  MODE 2: bf16 V^T (b,h,d,s).
// ---------------------------------------------------------------------------
template <int MODE>
__device__ __forceinline__ void mm_body(const bf16* __restrict__ A,
                                        const bf16* __restrict__ W,
                                        const float* __restrict__ bias,
                                        void* __restrict__ Cp, float scale) {
  __shared__ __align__(16) bf16 As[2][128 * 32];
  __shared__ __align__(16) bf16 Bs[2][128 * 32];
  const int tid = threadIdx.x;
  const int lane = tid & 63;
  const int wid = tid >> 6;
  const int wr = wid >> 1, wc = wid & 1;
  const int fr = lane & 15, fg = lane >> 4;
  const int bm = blockIdx.x * 128, bn = blockIdx.y * 128;
  const bf16* Ab = A + (size_t)bm * kH;
  const bf16* Wb = W + (size_t)bn * kH;
  const int srow = lane >> 2;
  const int scol = (lane & 3) * 8;
  const int rb0 = wid * 32, rb1 = wid * 32 + 16;

  f32x4 acc[4][4] = {};

#define MM_STAGE(buf, k0)                                                     \
  do {                                                                        \
    glds16(Ab + (size_t)(rb0 + srow) * kH + (k0) + scol, As[buf] + rb0 * 32); \
    glds16(Ab + (size_t)(rb1 + srow) * kH + (k0) + scol, As[buf] + rb1 * 32); \
    glds16(Wb + (size_t)(rb0 + srow) * kH + (k0) + scol, Bs[buf] + rb0 * 32); \
    glds16(Wb + (size_t)(rb1 + srow) * kH + (k0) + scol, Bs[buf] + rb1 * 32); \
  } while (0)

#define MM_COMPUTE(buf)                                                       \
  do {                                                                        \
    bf16x8 af[4], bfv[4];                                                     \
    _Pragma("unroll") for (int m = 0; m < 4; ++m) af[m] =                     \
        *(const bf16x8*)(As[buf] + (wr * 64 + m * 16 + fr) * 32 + fg * 8);    \
    _Pragma("unroll") for (int n = 0; n < 4; ++n) bfv[n] =                    \
        *(const bf16x8*)(Bs[buf] + (wc * 64 + n * 16 + fr) * 32 + fg * 8);    \
    _Pragma("unroll") for (int m = 0; m < 4; ++m)                             \
        _Pragma("unroll") for (int n = 0; n < 4; ++n) acc[m][n] =             \
            __builtin_amdgcn_mfma_f32_16x16x32_bf16(af[m], bfv[n],            \
                                                    acc[m][n], 0, 0, 0);      \
  } while (0)

  MM_STAGE(0, 0);
  __syncthreads();  // prologue drain: tile 0 resident
  for (int k0 = 0; k0 < kH; k0 += 64) {
    // phase A: stage k0+32 into buf1, compute buf0 (k0)
    MM_STAGE(1, k0 + 32);
    MM_COMPUTE(0);
    __syncthreads();  // buf1 landed; all reads of buf0 done
    // phase B: stage k0+64 into buf0, compute buf1 (k0+32)
    if (k0 + 64 < kH) MM_STAGE(0, k0 + 64);
    MM_COMPUTE(1);
    __syncthreads();  // buf0 landed; all reads of buf1 done
  }
#undef MM_STAGE
#undef MM_COMPUTE

#pragma unroll
  for (int n = 0; n < 4; ++n) {
    const int nabs = bn + wc * 64 + n * 16 + fr;
    const float bv = bias[nabs];
#pragma unroll
    for (int m = 0; m < 4; ++m) {
      if (MODE == 2) {
        const int tok0 = bm + wr * 64 + m * 16 + fg * 4;
        const int b = tok0 >> 11, s0 = tok0 & (kS - 1);
        const int h = nabs >> 6, d = nabs & 63;
        bf16x4 pv;
#pragma unroll
        for (int reg = 0; reg < 4; ++reg) pv[reg] = (bf16)(acc[m][n][reg] + bv);
        *(bf16x4*)((bf16*)Cp + (((size_t)(b * kNH + h) * kHD + d) * kS + s0)) = pv;
      } else {
#pragma unroll
        for (int reg = 0; reg < 4; ++reg) {
          const int tok = bm + wr * 64 + m * 16 + fg * 4 + reg;
          const float v = (acc[m][n][reg] + bv) * scale;
          if (MODE == 0) {
            ((float*)Cp)[(size_t)tok * kH + nabs] = v;
          } else {
            const int b = tok >> 11, s = tok & (kS - 1);
            const int h = nabs >> 6, d = nabs & 63;
            ((bf16*)Cp)[(((size_t)(b * kNH + h)) * kS + s) * kHD + d] = (bf16)v;
          }
        }
      }
    }
  }
}

__global__ __launch_bounds__(256) void qkv_kernel(
    const bf16* __restrict__ xb, const bf16* __restrict__ wb,
    const float* __restrict__ bq, const float* __restrict__ bk,
    const float* __restrict__ bv, bf16* __restrict__ qh,
    bf16* __restrict__ kh, bf16* __restrict__ vh) {
  const int z = blockIdx.z;
  const bf16* W = wb + (size_t)z * kH * kH;
  // Q pre-scaled by 1/sqrt(HD)*log2(e) so attention scores are exp2-ready.
  if (z == 0) mm_body<1>(xb, W, bq, qh, 0.125f * 1.44269504f);
  else if (z == 1) mm_body<1>(xb, W, bk, kh, 1.f);
  else mm_body<2>(xb, W, bv, vh, 1.f);
}

__global__ __launch_bounds__(256) void oproj_kernel(
    const bf16* __restrict__ ab, const bf16* __restrict__ wob,
    const float* __restrict__ bo, float* __restrict__ out) {
  mm_body<0>(ab, wob, bo, out, 1.f);
}

// ---------------------------------------------------------------------------
// LDS-staged swapped-QK^T MFMA flash attention, 32x32x16 bf16 (unchanged
// from R9: fixed-offset exp2 softmax, cvt_pk + permlane32_swap P-pack).
// ---------------------------------------------------------------------------
__global__ __launch_bounds__(256) void attn_kernel(
    const bf16* __restrict__ Qh, const bf16* __restrict__ Kh,
    const bf16* __restrict__ Vt, bf16* __restrict__ Ab) {
  __shared__ __align__(16) bf16 Ks[64 * 64];
  __shared__ __align__(16) bf16 Vs[64 * 64];
  const int tid = threadIdx.x;
  const int lane = tid & 63;
  const int wid = tid >> 6;
  const int l31 = lane & 31;
  const int hi = lane >> 5;
  const int bh = blockIdx.x;
  const int qt = gridDim.y - 1 - blockIdx.y;  // biggest q-tiles dispatch first
  const int b = bh >> 4, h = bh & (kNH - 1);

  const int qfirst = qt * 128 + wid * 32;
  const int qrow = qfirst + l31;

  const bf16* Qg = Qh + (size_t)bh * kS * kHD;
  const bf16* Kg = Kh + (size_t)bh * kS * kHD;  // [2048 s][64 d]
  const bf16* Vg = Vt + (size_t)bh * kHD * kS;  // [64 d][2048 s]

  // Q fragments (B-operand: B[k=d][col=q]), resident whole kernel
  bf16x8 qf[4];
#pragma unroll
  for (int kb = 0; kb < 4; ++kb)
    qf[kb] = *(const bf16x8*)(Qg + (size_t)qrow * kHD + kb * 16 + hi * 8);

  f32x16 Oa0 = {}, Oa1 = {};
  float lreg = 0.f;

  const int sr = tid >> 2;   // staging row
  const int sc = tid & 3;    // staging 16B chunk (and +4)
  const int nt64 = qt * 2 + 2;

  for (int kt = 0; kt < nt64; ++kt) {
    const int kt0 = kt * 64;
    const bf16x8 kr0 = *(const bf16x8*)(Kg + (size_t)(kt0 + sr) * kHD + sc * 8);
    const bf16x8 kr1 = *(const bf16x8*)(Kg + (size_t)(kt0 + sr) * kHD + (sc + 4) * 8);
    const bf16x8 vr0 = *(const bf16x8*)(Vg + (size_t)sr * kS + kt0 + sc * 8);
    const bf16x8 vr1 = *(const bf16x8*)(Vg + (size_t)sr * kS + kt0 + (sc + 4) * 8);
    __syncthreads();  // previous tile reads done
    *(bf16x8*)((char*)Ks + sr * 128 + ((sc ^ (sr & 7)) << 4)) = kr0;
    *(bf16x8*)((char*)Ks + sr * 128 + (((sc + 4) ^ (sr & 7)) << 4)) = kr1;
    *(bf16x8*)((char*)Vs + sr * 128 + ((sc ^ (sr & 7)) << 4)) = vr0;
    *(bf16x8*)((char*)Vs + sr * 128 + (((sc + 4) ^ (sr & 7)) << 4)) = vr1;
    __syncthreads();

#pragma unroll
    for (int st = 0; st < 2; ++st) {
      const int kabs = kt0 + st * 32;
      if (kabs > qfirst) continue;  // wave-uniform causal skip
      const bool diag = (kabs == qfirst);

      // ---- S^T = K . Q^T ----
      f32x16 S = {};
      {
        const int row = st * 32 + l31;
        const char* krow = (const char*)Ks + row * 128;
#pragma unroll
        for (int kb = 0; kb < 4; ++kb) {
          const int slot = (kb * 2 + hi) ^ (row & 7);
          const bf16x8 kf = *(const bf16x8*)(krow + slot * 16);
          S = __builtin_amdgcn_mfma_f32_32x32x16_bf16(kf, qf[kb], S, 0, 0, 0);
        }
      }
      // ---- V^T frags early (lgkm latency hides under softmax) ----
      bf16x8 vf0[2], vf1[2];
#pragma unroll
      for (int kb2 = 0; kb2 < 2; ++kb2) {
        const int d0 = l31, d1 = 32 + l31;
        const int c = st * 4 + kb2 * 2 + hi;
        vf0[kb2] = *(const bf16x8*)((char*)Vs + d0 * 128 + ((c ^ (d0 & 7)) << 4));
        vf1[kb2] = *(const bf16x8*)((char*)Vs + d1 * 128 + ((c ^ (d1 & 7)) << 4));
      }

      // ---- fixed-offset softmax: p = exp2(S - 8), no max tracking ----
      float p[16];
      float ps = 0.f;
      if (diag) {
#pragma unroll
        for (int r = 0; r < 16; ++r) {
          const int key = kabs + (r & 3) + 8 * (r >> 2) + 4 * hi;
          float s2 = S[r] - 8.f;
          if (key > qrow) s2 = -3.0e38f;  // exp2 -> 0
          p[r] = exp2a(s2);
          ps += p[r];
        }
      } else {
#pragma unroll
        for (int r = 0; r < 16; ++r) {
          p[r] = exp2a(S[r] - 8.f);
          ps += p[r];
        }
      }
      ps += __shfl_xor(ps, 32, 64);
      lreg += ps;

      // ---- pack P -> bf16 B-frags via cvt_pk + permlane32_swap ----
      bf16x8 pf[2];
#pragma unroll
      for (int kb2 = 0; kb2 < 2; ++kb2) {
        const int o = kb2 * 8;
        unsigned a01 = cvtpk(p[o + 0], p[o + 1]);
        unsigned a45 = cvtpk(p[o + 4], p[o + 5]);
        asm("v_permlane32_swap_b32 %0, %1" : "+v"(a01), "+v"(a45));
        unsigned a23 = cvtpk(p[o + 2], p[o + 3]);
        unsigned a67 = cvtpk(p[o + 6], p[o + 7]);
        asm("v_permlane32_swap_b32 %0, %1" : "+v"(a23), "+v"(a67));
        union { unsigned u[4]; bf16x8 v; } t;
        t.u[0] = a01; t.u[1] = a23; t.u[2] = a45; t.u[3] = a67;
        pf[kb2] = t.v;
      }

      // ---- O^T += V^T . P^T ----
#pragma unroll
      for (int kb2 = 0; kb2 < 2; ++kb2) {
        Oa0 = __builtin_amdgcn_mfma_f32_32x32x16_bf16(vf0[kb2], pf[kb2], Oa0, 0, 0, 0);
        Oa1 = __builtin_amdgcn_mfma_f32_32x32x16_bf16(vf1[kb2], pf[kb2], Oa1, 0, 0, 0);
      }
    }
  }

  // ---- normalize + store bf16 (B,S,H) ----
  const float rl = 1.f / lreg;
  bf16* const orow = Ab + ((size_t)b * kS + qrow) * kH + h * 64;
#pragma unroll
  for (int rq = 0; rq < 4; ++rq) {
    bf16x4 o0, o1;
#pragma unroll
    for (int j = 0; j < 4; ++j) {
      o0[j] = (bf16)(Oa0[rq * 4 + j] * rl);
      o1[j] = (bf16)(Oa1[rq * 4 + j] * rl);
    }
    *(bf16x4*)(orow + rq * 8 + hi * 4) = o0;
    *(bf16x4*)(orow + 32 + rq * 8 + hi * 4) = o1;
  }
}

extern "C" void kernel_launch(void* const* d_in, const int* in_sizes, int n_in,
                              void* d_out, int out_size, void* d_ws,
                              size_t ws_size, hipStream_t stream) {
  const float* x = (const float*)d_in[0];
  const float* wq = (const float*)d_in[1];
  const float* bq = (const float*)d_in[2];
  const float* wk = (const float*)d_in[3];
  const float* bk = (const float*)d_in[4];
  const float* wv = (const float*)d_in[5];
  const float* bv = (const float*)d_in[6];
  const float* wo = (const float*)d_in[7];
  const float* bo = (const float*)d_in[8];
  float* out = (float*)d_out;

  const size_t perHead = (size_t)kB * kNH * kS * kHD;
  bf16* xb = (bf16*)d_ws;
  bf16* wb = xb + (size_t)kM * kH;
  bf16* qh = wb + (size_t)4 * kH * kH;
  bf16* kh = qh + perHead;
  bf16* vh = kh + perHead;   // V^T: [bh][64][2048]
  bf16* ab = vh + perHead;   // attn out, (B,S,H) bf16

  dim3 blk(256);
  cvt_all_kernel<<<dim3(kM + 4 * 1024), blk, 0, stream>>>(x, wq, wk, wv, wo,
                                                          xb, wb);
  qkv_kernel<<<dim3(kM / 128, kH / 128, 3), blk, 0, stream>>>(
      xb, wb, bq, bk, bv, qh, kh, vh);
  attn_kernel<<<dim3(kB * kNH, kS / 128), blk, 0, stream>>>(qh, kh, vh, ab);
  oproj_kernel<<<dim3(kM / 128, kH / 128), blk, 0, stream>>>(
      ab, wb + (size_t)3 * kH * kH, bo, out);
}

// Round 11
// 160.956 us; speedup vs baseline: 1.0697x; 1.0697x over previous
//
#include <hip/hip_runtime.h>
#include <hip/hip_bf16.h>

using bf16 = __bf16;
typedef __attribute__((ext_vector_type(4))) bf16 bf16x4;
typedef __attribute__((ext_vector_type(8))) bf16 bf16x8;
typedef __attribute__((ext_vector_type(4))) float f32x4;
typedef __attribute__((ext_vector_type(16))) float f32x16;

constexpr int kB = 4, kS = 2048, kH = 1024, kNH = 16, kHD = 64;
constexpr int kM = kB * kS;  // 8192

__device__ __forceinline__ float exp2a(float x) {
  float r;
  asm("v_exp_f32 %0, %1" : "=v"(r) : "v"(x));
  return r;
}
// packed f32x2 -> bf16x2 (lo = a, hi = b), single instruction (T12)
__device__ __forceinline__ unsigned cvtpk(float a, float b) {
  unsigned r;
  asm("v_cvt_pk_bf16_f32 %0, %1, %2" : "=v"(r) : "v"(a), "v"(b));
  return r;
}
// async global->LDS, 16B per lane; LDS dest = wave-uniform base + lane*16
__device__ __forceinline__ void glds16(const bf16* g, bf16* l) {
  __builtin_amdgcn_global_load_lds(
      (const __attribute__((address_space(1))) unsigned*)g,
      (__attribute__((address_space(3))) unsigned*)l, 16, 0, 0);
}

// ---------------------------------------------------------------------------
// fused fp32 -> bf16 conversion (x + 4 weight matrices) in one launch
// ---------------------------------------------------------------------------
__global__ __launch_bounds__(256) void cvt_all_kernel(
    const float* __restrict__ x, const float* __restrict__ w0,
    const float* __restrict__ w1, const float* __restrict__ w2,
    const float* __restrict__ w3, bf16* __restrict__ xb,
    bf16* __restrict__ wb) {
  const int blk = blockIdx.x;
  const float* src;
  bf16* dst;
  int rel;
  if (blk < kM) {
    src = x; dst = xb; rel = blk;
  } else {
    const int wi = (blk - kM) >> 10;
    rel = (blk - kM) & 1023;
    src = wi == 0 ? w0 : wi == 1 ? w1 : wi == 2 ? w2 : w3;
    dst = wb + (size_t)wi * kH * kH;
  }
  const size_t i = (size_t)rel * 256 + threadIdx.x;
  const float4 f = ((const float4*)src)[i];
  bf16x4 o;
  o[0] = (bf16)f.x; o[1] = (bf16)f.y; o[2] = (bf16)f.z; o[3] = (bf16)f.w;
  ((bf16x4*)dst)[i] = o;
}

// ---------------------------------------------------------------------------
// bf16 MFMA GEMM (m97 structure, BK=64 as 2x32 sub-tiles): C = (A @ W^T +
// bias) * scale.  128x128 tile, 4 waves, async global_load_lds into LINEAR
// LDS.  Two [128][32] sub-tiles staged together -> ONE barrier pair per 64 K
// (half of R9's count), same 32KB LDS, same frag addressing.
// MODE 0: fp32 [M][kH].  MODE 1: bf16 (b,h,s,d).  MODE 2: bf16 V^T (b,h,d,s).
// ---------------------------------------------------------------------------
template <int MODE>
__device__ __forceinline__ void mm_body(const bf16* __restrict__ A,
                                        const bf16* __restrict__ W,
                                        const float* __restrict__ bias,
                                        void* __restrict__ Cp, float scale) {
  __shared__ __align__(16) bf16 As[2][128 * 32];
  __shared__ __align__(16) bf16 Bs[2][128 * 32];
  const int tid = threadIdx.x;
  const int lane = tid & 63;
  const int wid = tid >> 6;
  const int wr = wid >> 1, wc = wid & 1;
  const int fr = lane & 15, fg = lane >> 4;
  const int bm = blockIdx.x * 128, bn = blockIdx.y * 128;
  const bf16* Ab = A + (size_t)bm * kH;
  const bf16* Wb = W + (size_t)bn * kH;
  const int srow = lane >> 2;
  const int scol = (lane & 3) * 8;
  const int rb0 = wid * 32, rb1 = wid * 32 + 16;

  f32x4 acc[4][4] = {};

  for (int k0 = 0; k0 < kH; k0 += 64) {
    __syncthreads();  // all waves done reading previous tiles
    // stage both 32-K sub-tiles (8 glds16/wave)
    glds16(Ab + (size_t)(rb0 + srow) * kH + k0 + scol, As[0] + rb0 * 32);
    glds16(Ab + (size_t)(rb1 + srow) * kH + k0 + scol, As[0] + rb1 * 32);
    glds16(Ab + (size_t)(rb0 + srow) * kH + k0 + 32 + scol, As[1] + rb0 * 32);
    glds16(Ab + (size_t)(rb1 + srow) * kH + k0 + 32 + scol, As[1] + rb1 * 32);
    glds16(Wb + (size_t)(rb0 + srow) * kH + k0 + scol, Bs[0] + rb0 * 32);
    glds16(Wb + (size_t)(rb1 + srow) * kH + k0 + scol, Bs[0] + rb1 * 32);
    glds16(Wb + (size_t)(rb0 + srow) * kH + k0 + 32 + scol, Bs[1] + rb0 * 32);
    glds16(Wb + (size_t)(rb1 + srow) * kH + k0 + 32 + scol, Bs[1] + rb1 * 32);
    __syncthreads();  // vmcnt drain -> both sub-tiles visible

#pragma unroll
    for (int s = 0; s < 2; ++s) {
      bf16x8 af[4], bfv[4];
#pragma unroll
      for (int m = 0; m < 4; ++m)
        af[m] = *(const bf16x8*)(As[s] + (wr * 64 + m * 16 + fr) * 32 + fg * 8);
#pragma unroll
      for (int n = 0; n < 4; ++n)
        bfv[n] = *(const bf16x8*)(Bs[s] + (wc * 64 + n * 16 + fr) * 32 + fg * 8);
#pragma unroll
      for (int m = 0; m < 4; ++m)
#pragma unroll
        for (int n = 0; n < 4; ++n)
          acc[m][n] = __builtin_amdgcn_mfma_f32_16x16x32_bf16(
              af[m], bfv[n], acc[m][n], 0, 0, 0);
    }
  }

#pragma unroll
  for (int n = 0; n < 4; ++n) {
    const int nabs = bn + wc * 64 + n * 16 + fr;
    const float bv = bias[nabs];
#pragma unroll
    for (int m = 0; m < 4; ++m) {
      if (MODE == 2) {
        const int tok0 = bm + wr * 64 + m * 16 + fg * 4;
        const int b = tok0 >> 11, s0 = tok0 & (kS - 1);
        const int h = nabs >> 6, d = nabs & 63;
        bf16x4 pv;
#pragma unroll
        for (int reg = 0; reg < 4; ++reg) pv[reg] = (bf16)(acc[m][n][reg] + bv);
        *(bf16x4*)((bf16*)Cp + (((size_t)(b * kNH + h) * kHD + d) * kS + s0)) = pv;
      } else {
#pragma unroll
        for (int reg = 0; reg < 4; ++reg) {
          const int tok = bm + wr * 64 + m * 16 + fg * 4 + reg;
          const float v = (acc[m][n][reg] + bv) * scale;
          if (MODE == 0) {
            ((float*)Cp)[(size_t)tok * kH + nabs] = v;
          } else {
            const int b = tok >> 11, s = tok & (kS - 1);
            const int h = nabs >> 6, d = nabs & 63;
            ((bf16*)Cp)[(((size_t)(b * kNH + h)) * kS + s) * kHD + d] = (bf16)v;
          }
        }
      }
    }
  }
}

__global__ __launch_bounds__(256) void qkv_kernel(
    const bf16* __restrict__ xb, const bf16* __restrict__ wb,
    const float* __restrict__ bq, const float* __restrict__ bk,
    const float* __restrict__ bv, bf16* __restrict__ qh,
    bf16* __restrict__ kh, bf16* __restrict__ vh) {
  const int z = blockIdx.z;
  const bf16* W = wb + (size_t)z * kH * kH;
  // Q pre-scaled by 1/sqrt(HD)*log2(e) so attention scores are exp2-ready.
  if (z == 0) mm_body<1>(xb, W, bq, qh, 0.125f * 1.44269504f);
  else if (z == 1) mm_body<1>(xb, W, bk, kh, 1.f);
  else mm_body<2>(xb, W, bv, vh, 1.f);
}

__global__ __launch_bounds__(256) void oproj_kernel(
    const bf16* __restrict__ ab, const bf16* __restrict__ wob,
    const float* __restrict__ bo, float* __restrict__ out) {
  mm_body<0>(ab, wob, bo, out, 1.f);
}

// ---------------------------------------------------------------------------
// LDS-staged swapped-QK^T MFMA flash attention, 32x32x16 bf16 (unchanged
// from R9: fixed-offset exp2 softmax, cvt_pk + permlane32_swap P-pack).
// ---------------------------------------------------------------------------
__global__ __launch_bounds__(256) void attn_kernel(
    const bf16* __restrict__ Qh, const bf16* __restrict__ Kh,
    const bf16* __restrict__ Vt, bf16* __restrict__ Ab) {
  __shared__ __align__(16) bf16 Ks[64 * 64];
  __shared__ __align__(16) bf16 Vs[64 * 64];
  const int tid = threadIdx.x;
  const int lane = tid & 63;
  const int wid = tid >> 6;
  const int l31 = lane & 31;
  const int hi = lane >> 5;
  const int bh = blockIdx.x;
  const int qt = gridDim.y - 1 - blockIdx.y;  // biggest q-tiles dispatch first
  const int b = bh >> 4, h = bh & (kNH - 1);

  const int qfirst = qt * 128 + wid * 32;
  const int qrow = qfirst + l31;

  const bf16* Qg = Qh + (size_t)bh * kS * kHD;
  const bf16* Kg = Kh + (size_t)bh * kS * kHD;  // [2048 s][64 d]
  const bf16* Vg = Vt + (size_t)bh * kHD * kS;  // [64 d][2048 s]

  // Q fragments (B-operand: B[k=d][col=q]), resident whole kernel
  bf16x8 qf[4];
#pragma unroll
  for (int kb = 0; kb < 4; ++kb)
    qf[kb] = *(const bf16x8*)(Qg + (size_t)qrow * kHD + kb * 16 + hi * 8);

  f32x16 Oa0 = {}, Oa1 = {};
  float lreg = 0.f;

  const int sr = tid >> 2;   // staging row
  const int sc = tid & 3;    // staging 16B chunk (and +4)
  const int nt64 = qt * 2 + 2;

  for (int kt = 0; kt < nt64; ++kt) {
    const int kt0 = kt * 64;
    const bf16x8 kr0 = *(const bf16x8*)(Kg + (size_t)(kt0 + sr) * kHD + sc * 8);
    const bf16x8 kr1 = *(const bf16x8*)(Kg + (size_t)(kt0 + sr) * kHD + (sc + 4) * 8);
    const bf16x8 vr0 = *(const bf16x8*)(Vg + (size_t)sr * kS + kt0 + sc * 8);
    const bf16x8 vr1 = *(const bf16x8*)(Vg + (size_t)sr * kS + kt0 + (sc + 4) * 8);
    __syncthreads();  // previous tile reads done
    *(bf16x8*)((char*)Ks + sr * 128 + ((sc ^ (sr & 7)) << 4)) = kr0;
    *(bf16x8*)((char*)Ks + sr * 128 + (((sc + 4) ^ (sr & 7)) << 4)) = kr1;
    *(bf16x8*)((char*)Vs + sr * 128 + ((sc ^ (sr & 7)) << 4)) = vr0;
    *(bf16x8*)((char*)Vs + sr * 128 + (((sc + 4) ^ (sr & 7)) << 4)) = vr1;
    __syncthreads();

#pragma unroll
    for (int st = 0; st < 2; ++st) {
      const int kabs = kt0 + st * 32;
      if (kabs > qfirst) continue;  // wave-uniform causal skip
      const bool diag = (kabs == qfirst);

      // ---- S^T = K . Q^T ----
      f32x16 S = {};
      {
        const int row = st * 32 + l31;
        const char* krow = (const char*)Ks + row * 128;
#pragma unroll
        for (int kb = 0; kb < 4; ++kb) {
          const int slot = (kb * 2 + hi) ^ (row & 7);
          const bf16x8 kf = *(const bf16x8*)(krow + slot * 16);
          S = __builtin_amdgcn_mfma_f32_32x32x16_bf16(kf, qf[kb], S, 0, 0, 0);
        }
      }
      // ---- V^T frags early (lgkm latency hides under softmax) ----
      bf16x8 vf0[2], vf1[2];
#pragma unroll
      for (int kb2 = 0; kb2 < 2; ++kb2) {
        const int d0 = l31, d1 = 32 + l31;
        const int c = st * 4 + kb2 * 2 + hi;
        vf0[kb2] = *(const bf16x8*)((char*)Vs + d0 * 128 + ((c ^ (d0 & 7)) << 4));
        vf1[kb2] = *(const bf16x8*)((char*)Vs + d1 * 128 + ((c ^ (d1 & 7)) << 4));
      }

      // ---- fixed-offset softmax: p = exp2(S - 8), no max tracking ----
      float p[16];
      float ps = 0.f;
      if (diag) {
#pragma unroll
        for (int r = 0; r < 16; ++r) {
          const int key = kabs + (r & 3) + 8 * (r >> 2) + 4 * hi;
          float s2 = S[r] - 8.f;
          if (key > qrow) s2 = -3.0e38f;  // exp2 -> 0
          p[r] = exp2a(s2);
          ps += p[r];
        }
      } else {
#pragma unroll
        for (int r = 0; r < 16; ++r) {
          p[r] = exp2a(S[r] - 8.f);
          ps += p[r];
        }
      }
      ps += __shfl_xor(ps, 32, 64);
      lreg += ps;

      // ---- pack P -> bf16 B-frags via cvt_pk + permlane32_swap ----
      bf16x8 pf[2];
#pragma unroll
      for (int kb2 = 0; kb2 < 2; ++kb2) {
        const int o = kb2 * 8;
        unsigned a01 = cvtpk(p[o + 0], p[o + 1]);
        unsigned a45 = cvtpk(p[o + 4], p[o + 5]);
        asm("v_permlane32_swap_b32 %0, %1" : "+v"(a01), "+v"(a45));
        unsigned a23 = cvtpk(p[o + 2], p[o + 3]);
        unsigned a67 = cvtpk(p[o + 6], p[o + 7]);
        asm("v_permlane32_swap_b32 %0, %1" : "+v"(a23), "+v"(a67));
        union { unsigned u[4]; bf16x8 v; } t;
        t.u[0] = a01; t.u[1] = a23; t.u[2] = a45; t.u[3] = a67;
        pf[kb2] = t.v;
      }

      // ---- O^T += V^T . P^T ----
#pragma unroll
      for (int kb2 = 0; kb2 < 2; ++kb2) {
        Oa0 = __builtin_amdgcn_mfma_f32_32x32x16_bf16(vf0[kb2], pf[kb2], Oa0, 0, 0, 0);
        Oa1 = __builtin_amdgcn_mfma_f32_32x32x16_bf16(vf1[kb2], pf[kb2], Oa1, 0, 0, 0);
      }
    }
  }

  // ---- normalize + store bf16 (B,S,H) ----
  const float rl = 1.f / lreg;
  bf16* const orow = Ab + ((size_t)b * kS + qrow) * kH + h * 64;
#pragma unroll
  for (int rq = 0; rq < 4; ++rq) {
    bf16x4 o0, o1;
#pragma unroll
    for (int j = 0; j < 4; ++j) {
      o0[j] = (bf16)(Oa0[rq * 4 + j] * rl);
      o1[j] = (bf16)(Oa1[rq * 4 + j] * rl);
    }
    *(bf16x4*)(orow + rq * 8 + hi * 4) = o0;
    *(bf16x4*)(orow + 32 + rq * 8 + hi * 4) = o1;
  }
}

extern "C" void kernel_launch(void* const* d_in, const int* in_sizes, int n_in,
                              void* d_out, int out_size, void* d_ws,
                              size_t ws_size, hipStream_t stream) {
  const float* x = (const float*)d_in[0];
  const float* wq = (const float*)d_in[1];
  const float* bq = (const float*)d_in[2];
  const float* wk = (const float*)d_in[3];
  const float* bk = (const float*)d_in[4];
  const float* wv = (const float*)d_in[5];
  const float* bv = (const float*)d_in[6];
  const float* wo = (const float*)d_in[7];
  const float* bo = (const float*)d_in[8];
  float* out = (float*)d_out;

  const size_t perHead = (size_t)kB * kNH * kS * kHD;
  bf16* xb = (bf16*)d_ws;
  bf16* wb = xb + (size_t)kM * kH;
  bf16* qh = wb + (size_t)4 * kH * kH;
  bf16* kh = qh + perHead;
  bf16* vh = kh + perHead;   // V^T: [bh][64][2048]
  bf16* ab = vh + perHead;   // attn out, (B,S,H) bf16

  dim3 blk(256);
  cvt_all_kernel<<<dim3(kM + 4 * 1024), blk, 0, stream>>>(x, wq, wk, wv, wo,
                                                          xb, wb);
  qkv_kernel<<<dim3(kM / 128, kH / 128, 3), blk, 0, stream>>>(
      xb, wb, bq, bk, bv, qh, kh, vh);
  attn_kernel<<<dim3(kB * kNH, kS / 128), blk, 0, stream>>>(qh, kh, vh, ab);
  oproj_kernel<<<dim3(kM / 128, kH / 128), blk, 0, stream>>>(
      ab, wb + (size_t)3 * kH * kH, bo, out);
}